// Round 16
// baseline (508.609 us; speedup 1.0000x reference)
//
#include <hip/hip_runtime.h>
#include <hip/hip_bf16.h>
#include <math.h>

#define L_TOK 1569
#define DM 192
#define DI 384
#define DS 16
#define DTR 12
#define DCONV 4
#define XDBL_N (DTR + 2*DS)   // 44
#define DEPTH 8
#define NCHUNK 50
#define CLEN 32
#define NPATCH 1568
#define NDG 24                // scan d-groups (384/16)

typedef __attribute__((ext_vector_type(8))) short short8;
typedef __attribute__((ext_vector_type(8))) unsigned short us8;
typedef __attribute__((ext_vector_type(4))) float f32x4;

__device__ __forceinline__ unsigned short f2bf(float f) {
  unsigned int u = __float_as_uint(f);
  u += 0x7FFFu + ((u >> 16) & 1u);   // round-to-nearest-even
  return (unsigned short)(u >> 16);
}

__device__ __forceinline__ float bf2f(unsigned short h) {
  return __uint_as_float(((unsigned int)h) << 16);
}

// sizes (elements) of converted weight blocks
#define PW_N  (192*768)
#define WIN_N (DEPTH*2*DI*DM)
#define WX_N  (DEPTH*XDBL_N*DI)
#define WO_N  (DEPTH*DM*DI)

__device__ __forceinline__ void cv8(const float* __restrict__ s,
                                    unsigned short* __restrict__ d, int i) {
  float4 a = *(const float4*)(s + (size_t)i*8);
  float4 b = *(const float4*)(s + (size_t)i*8 + 4);
  us8 o;
  o[0]=f2bf(a.x); o[1]=f2bf(a.y); o[2]=f2bf(a.z); o[3]=f2bf(a.w);
  o[4]=f2bf(b.x); o[5]=f2bf(b.y); o[6]=f2bf(b.z); o[7]=f2bf(b.w);
  *(us8*)(d + (size_t)i*8) = o;
}

// ---------------------------------------------------------------------------
// init: cur[tok][e] = pos + (tok==0 ? cls : patch_b); also converts all MFMA
// B-operand weights to bf16 (one-time, stream-ordered before first use).
// ---------------------------------------------------------------------------
__global__ __launch_bounds__(256) void init_kernel(
    const float* __restrict__ cls, const float* __restrict__ pb,
    const float* __restrict__ pos, float* __restrict__ curp,
    const float* __restrict__ pw,  const float* __restrict__ wi,
    const float* __restrict__ wx,  const float* __restrict__ wo,
    unsigned short* __restrict__ pwb, unsigned short* __restrict__ winb,
    unsigned short* __restrict__ wxb, unsigned short* __restrict__ wob) {
  int tid0 = blockIdx.x * 256 + threadIdx.x;
  int NT = gridDim.x * 256;
  const int initN = (L_TOK * DM) / 4;
  for (int gid = tid0; gid < initN; gid += NT) {
    int e4 = gid * 4;
    int tok = e4 / DM;
    int col = e4 % DM;
    float4 pv = *(const float4*)(pos + e4);
    float4 av = (tok == 0) ? *(const float4*)(cls + col)
                           : *(const float4*)(pb + col);
    float4 o = {pv.x + av.x, pv.y + av.y, pv.z + av.z, pv.w + av.w};
    *(float4*)(curp + e4) = o;
  }
  for (int i = tid0; i < PW_N/8;  i += NT) cv8(pw, pwb, i);
  for (int i = tid0; i < WIN_N/8; i += NT) cv8(wi, winb, i);
  for (int i = tid0; i < WX_N/8;  i += NT) cv8(wx, wxb, i);
  for (int i = tid0; i < WO_N/8;  i += NT) cv8(wo, wob, i);
}

// ---------------------------------------------------------------------------
// Final LayerNorm. One wave per token.
// ---------------------------------------------------------------------------
__global__ __launch_bounds__(64) void ln_kernel(
    const float* __restrict__ in, float* __restrict__ out,
    const float* __restrict__ g, const float* __restrict__ b) {
  int tokn = blockIdx.x;
  int lane = threadIdx.x;
  const float* row = in + (size_t)tokn*DM;
  float x0 = row[lane], x1 = row[lane+64], x2 = row[lane+128];
  float s = x0 + x1 + x2;
  float s2 = x0*x0 + x1*x1 + x2*x2;
#pragma unroll
  for (int off = 1; off < 64; off <<= 1) {
    s  += __shfl_xor(s,  off, 64);
    s2 += __shfl_xor(s2, off, 64);
  }
  float m = s * (1.0f/192.0f);
  float v = s2 * (1.0f/192.0f) - m*m;
  float rs = rsqrtf(v + 1e-5f);
  float* orow = out + (size_t)tokn*DM;
  orow[lane]     = (x0 - m)*rs*g[lane]     + b[lane];
  orow[lane+64]  = (x1 - m)*rs*g[lane+64]  + b[lane+64];
  orow[lane+128] = (x2 - m)*rs*g[lane+128] + b[lane+128];
}

// ---------------------------------------------------------------------------
// Patch GEMM, im2col fused into A-staging, bf16 weights:
// cur[1..][:] += X_patch @ patch_w^T. M=1568, N=192, K=768, split-K 8.
// ---------------------------------------------------------------------------
__device__ __forceinline__ float4 ldx4(const float* __restrict__ x,
                                       int pt, int hh, int w, int k) {
  int c = k >> 8, p = (k >> 4) & 15, q = k & 15;
  return *(const float4*)(x + ((size_t)(c*8 + pt)*224 + hh*16 + p)*224
                            + w*16 + q);
}

__global__ __launch_bounds__(256) void patch_gemm(
    const float* __restrict__ x, const unsigned short* __restrict__ pw,
    float* __restrict__ C) {
  __shared__ unsigned short As[64*40];
  __shared__ unsigned short Bs[64*40];
  int tid = threadIdx.x;
  int m0 = blockIdx.y * 64, n0 = blockIdx.x * 64;
  int kbase = blockIdx.z * 96;
  int wave = tid >> 6, lane = tid & 63;
  int wr = wave >> 1, wc = wave & 1;
  int srow = tid >> 2;
  int skq  = (tid & 3) * 8;
  f32x4 acc[2][2];
#pragma unroll
  for (int i = 0; i < 2; ++i)
#pragma unroll
    for (int j = 0; j < 2; ++j) acc[i][j] = (f32x4){0.f,0.f,0.f,0.f};

  int am = m0 + srow;
  bool a_ok = (am < NPATCH);
  int am_s = a_ok ? am : 0;
  int pt = am_s / 196, hw = am_s % 196, hh = hw / 14, w = hw % 14;
  int bn = n0 + srow;
  const unsigned short* bp = pw + (size_t)bn*768 + kbase + skq;
  const float4 z4 = {0.f,0.f,0.f,0.f};
  const us8 z8 = {0,0,0,0,0,0,0,0};
  int l15 = lane & 15, lk = (lane >> 4) * 8;

  const int nt = 3;   // 96/32
  float4 a0 = a_ok ? ldx4(x, pt, hh, w, kbase + skq)     : z4;
  float4 a1 = a_ok ? ldx4(x, pt, hh, w, kbase + skq + 4) : z4;
  us8 bv = *(const us8*)(bp);

  for (int i = 0; i < nt; ++i) {
    {
      short8 pa;
      pa[0]=f2bf(a0.x); pa[1]=f2bf(a0.y); pa[2]=f2bf(a0.z); pa[3]=f2bf(a0.w);
      pa[4]=f2bf(a1.x); pa[5]=f2bf(a1.y); pa[6]=f2bf(a1.z); pa[7]=f2bf(a1.w);
      *(short8*)&As[srow*40 + skq] = pa;
      *(us8*)&Bs[srow*40 + skq] = bv;
    }
    __syncthreads();
    bool pf = (i + 1 < nt);
    int kn = kbase + ((i + 1) << 5) + skq;
    a0 = (pf && a_ok) ? ldx4(x, pt, hh, w, kn)     : z4;
    a1 = (pf && a_ok) ? ldx4(x, pt, hh, w, kn + 4) : z4;
    bv = pf ? *(const us8*)(bp + ((i+1)<<5)) : z8;

    short8 af0 = *(const short8*)&As[(wr*32      + l15)*40 + lk];
    short8 af1 = *(const short8*)&As[(wr*32 + 16 + l15)*40 + lk];
    short8 bf0 = *(const short8*)&Bs[(wc*32      + l15)*40 + lk];
    short8 bf1 = *(const short8*)&Bs[(wc*32 + 16 + l15)*40 + lk];
    acc[0][0] = __builtin_amdgcn_mfma_f32_16x16x32_bf16(af0, bf0, acc[0][0], 0, 0, 0);
    acc[0][1] = __builtin_amdgcn_mfma_f32_16x16x32_bf16(af0, bf1, acc[0][1], 0, 0, 0);
    acc[1][0] = __builtin_amdgcn_mfma_f32_16x16x32_bf16(af1, bf0, acc[1][0], 0, 0, 0);
    acc[1][1] = __builtin_amdgcn_mfma_f32_16x16x32_bf16(af1, bf1, acc[1][1], 0, 0, 0);
    __syncthreads();
  }

#pragma unroll
  for (int r = 0; r < 2; ++r) {
#pragma unroll
    for (int c = 0; c < 2; ++c) {
      int col = n0 + wc*32 + c*16 + l15;
      int rowb = m0 + wr*32 + r*16 + (lane >> 4)*4;
#pragma unroll
      for (int j = 0; j < 4; ++j) {
        int row = rowb + j;
        if (row < NPATCH)
          atomicAdd(C + (size_t)row*DM + col, acc[r][c][j]);
      }
    }
  }
}

// ---------------------------------------------------------------------------
// Fused LN + xz GEMM, BN=128 (LN computed once per 128 output cols).
// grid (6, 25). Output xz bf16. Zeroes xdbl (bx==0).
// ---------------------------------------------------------------------------
__global__ __launch_bounds__(256) void lnxz_kernel(
    const float* __restrict__ cur, const float* __restrict__ g,
    const float* __restrict__ b, const unsigned short* __restrict__ W,
    unsigned short* __restrict__ xzb, float* __restrict__ xdbl_z) {
  __shared__ unsigned short As[64][200];
  __shared__ unsigned short Bs[128][200];
  __shared__ float gs[192], bs2[192];
  int tid = threadIdx.x;
  int m0 = blockIdx.y * 64, n0 = blockIdx.x * 128;
  int wave = tid >> 6, lane = tid & 63;
  int wr = wave >> 1, wcq = wave & 1;
  int l15 = lane & 15, lk = (lane >> 4) * 8;

  for (int i = tid; i < 192; i += 256) { gs[i] = g[i]; bs2[i] = b[i]; }

  if (blockIdx.x == 0) {
    for (int i = tid; i < 64*11; i += 256) {
      int r = i / 11, q = i % 11;
      int row = m0 + r;
      if (row < L_TOK) {
        float4 z = {0.f,0.f,0.f,0.f};
        *(float4*)(xdbl_z + (size_t)row*XDBL_N + q*4) = z;
      }
    }
  }

  int r = tid >> 2, c0 = (tid & 3) * 48;
  float v[48];
  {
    int row = m0 + r;
    if (row < L_TOK) {
      const float* rp = cur + (size_t)row*DM + c0;
#pragma unroll
      for (int j = 0; j < 12; ++j) {
        float4 t4 = *(const float4*)(rp + j*4);
        v[j*4+0]=t4.x; v[j*4+1]=t4.y; v[j*4+2]=t4.z; v[j*4+3]=t4.w;
      }
    } else {
#pragma unroll
      for (int j = 0; j < 48; ++j) v[j] = 0.f;
    }
  }
  float s = 0.f, s2 = 0.f;
#pragma unroll
  for (int j = 0; j < 48; ++j) { s += v[j]; s2 += v[j]*v[j]; }
  s  += __shfl_xor(s, 1, 64); s2 += __shfl_xor(s2, 1, 64);
  s  += __shfl_xor(s, 2, 64); s2 += __shfl_xor(s2, 2, 64);
  float mu = s * (1.0f/192.0f);
  float var = s2 * (1.0f/192.0f) - mu*mu;
  float rsd = rsqrtf(var + 1e-5f);

  __syncthreads();
#pragma unroll
  for (int j = 0; j < 48; ++j) {
    int k = c0 + j;
    As[r][k] = f2bf((v[j] - mu)*rsd*gs[k] + bs2[k]);
  }
  for (int i = tid; i < 128*24; i += 256) {
    int row = i / 24, q = i % 24;
    *(us8*)&Bs[row][q*8] = *(const us8*)(W + (size_t)(n0 + row)*DM + q*8);
  }
  __syncthreads();

  f32x4 acc[2][4];
#pragma unroll
  for (int i = 0; i < 2; ++i)
#pragma unroll
    for (int j = 0; j < 4; ++j) acc[i][j] = (f32x4){0.f,0.f,0.f,0.f};

#pragma unroll
  for (int kk = 0; kk < 6; ++kk) {
    short8 af0 = *(const short8*)&As[wr*32      + l15][kk*32 + lk];
    short8 af1 = *(const short8*)&As[wr*32 + 16 + l15][kk*32 + lk];
#pragma unroll
    for (int cc = 0; cc < 4; ++cc) {
      short8 bf = *(const short8*)&Bs[wcq*64 + cc*16 + l15][kk*32 + lk];
      acc[0][cc] = __builtin_amdgcn_mfma_f32_16x16x32_bf16(af0, bf, acc[0][cc], 0, 0, 0);
      acc[1][cc] = __builtin_amdgcn_mfma_f32_16x16x32_bf16(af1, bf, acc[1][cc], 0, 0, 0);
    }
  }

#pragma unroll
  for (int rr = 0; rr < 2; ++rr) {
#pragma unroll
    for (int cc = 0; cc < 4; ++cc) {
      int col = n0 + wcq*64 + cc*16 + l15;
      int rowb = m0 + wr*32 + rr*16 + (lane >> 4)*4;
#pragma unroll
      for (int j = 0; j < 4; ++j) {
        int row = rowb + j;
        if (row < L_TOK)
          xzb[(size_t)row*(2*DI) + col] = f2bf(acc[rr][cc][j]);
      }
    }
  }
}

// ---------------------------------------------------------------------------
// xdbl GEMM, conv+SiLU fused in A-staging; bf16 Wx; split-K 12 (one k-step).
// Exports u (bf16) to ucb. xdbl (f32) zero-init by lnxz. grid = (1, 25, 12).
// ---------------------------------------------------------------------------
__global__ __launch_bounds__(256) void cgemm_kernel(
    const unsigned short* __restrict__ xzb,
    const float* __restrict__ Wc, const float* __restrict__ bc,
    const unsigned short* __restrict__ B, float* __restrict__ C,
    unsigned short* __restrict__ ucb) {
  __shared__ unsigned short As[64*40];
  __shared__ unsigned short Bs[64*40];
  __shared__ float wcs[32][4];
  __shared__ float bcs[32];
  const int M = L_TOK, N = XDBL_N;
  int tid = threadIdx.x;
  int m0 = blockIdx.y * 64;
  int kbase = blockIdx.z * 32;
  int wave = tid >> 6, lane = tid & 63;
  int wr = wave >> 1, wcq = wave & 1;
  int srow = tid >> 2;
  int skq  = (tid & 3) * 8;
  if (tid < 32) {
    *(float4*)wcs[tid] = *(const float4*)(Wc + (size_t)(kbase + tid)*4);
    bcs[tid] = bc[kbase + tid];
  }

  int t = m0 + srow;
  bool a_ok = (t < M);
  bool b_ok = (srow < N);
  const unsigned short* bp = B + (size_t)srow*DI + kbase + skq;
  const us8 z8 = {0,0,0,0,0,0,0,0};
  int l15 = lane & 15, lk = (lane >> 4) * 8;
  int cg = kbase + skq;

  us8 tap[4];
#pragma unroll
  for (int j = 0; j < 4; ++j) {
    int ts = t - 3 + j;
    tap[j] = (a_ok && ts >= 0)
               ? *(const us8*)(xzb + (size_t)ts*(2*DI) + cg) : z8;
  }
  us8 bv = b_ok ? *(const us8*)(bp) : z8;
  __syncthreads();   // wcs/bcs ready

  short8 pa;
#pragma unroll
  for (int c = 0; c < 8; ++c) {
    float u = bcs[skq + c];
#pragma unroll
    for (int j = 0; j < 4; ++j)
      u = fmaf(bf2f(tap[j][c]), wcs[skq + c][j], u);
    u = u / (1.0f + expf(-u));
    pa[c] = (short)f2bf(u);
  }
  if (a_ok)
    *(short8*)(ucb + (size_t)t*DI + cg) = pa;
  *(short8*)&As[srow*40 + skq] = pa;
  *(us8*)&Bs[srow*40 + skq] = bv;
  __syncthreads();

  f32x4 acc[2][2];
#pragma unroll
  for (int i = 0; i < 2; ++i)
#pragma unroll
    for (int j = 0; j < 2; ++j) acc[i][j] = (f32x4){0.f,0.f,0.f,0.f};
  short8 af0 = *(const short8*)&As[(wr*32      + l15)*40 + lk];
  short8 af1 = *(const short8*)&As[(wr*32 + 16 + l15)*40 + lk];
  short8 bf0 = *(const short8*)&Bs[(wcq*32      + l15)*40 + lk];
  short8 bf1 = *(const short8*)&Bs[(wcq*32 + 16 + l15)*40 + lk];
  acc[0][0] = __builtin_amdgcn_mfma_f32_16x16x32_bf16(af0, bf0, acc[0][0], 0, 0, 0);
  acc[0][1] = __builtin_amdgcn_mfma_f32_16x16x32_bf16(af0, bf1, acc[0][1], 0, 0, 0);
  acc[1][0] = __builtin_amdgcn_mfma_f32_16x16x32_bf16(af1, bf0, acc[1][0], 0, 0, 0);
  acc[1][1] = __builtin_amdgcn_mfma_f32_16x16x32_bf16(af1, bf1, acc[1][1], 0, 0, 0);

#pragma unroll
  for (int r = 0; r < 2; ++r) {
#pragma unroll
    for (int c = 0; c < 2; ++c) {
      int col = wcq*32 + c*16 + l15;
      if (col >= N) continue;
      int rowb = m0 + wr*32 + r*16 + (lane >> 4)*4;
#pragma unroll
      for (int j = 0; j < 4; ++j) {
        int row = rowb + j;
        if (row >= M) continue;
        atomicAdd(C + (size_t)row*XDBL_N + col, acc[r][c][j]);
      }
    }
  }
}

// ---------------------------------------------------------------------------
// scan_p1: per-chunk local scan from zero state (CLEN=32).
// grid = (NDG, NCHUNK) = (24, 50), 256 thr = 16d x 16n. No delta export.
// ---------------------------------------------------------------------------
__global__ __launch_bounds__(256) void scan_p1(
    const unsigned short* __restrict__ ucb, const float* __restrict__ xdbl,
    const float* __restrict__ W_dt, const float* __restrict__ b_dt,
    const float* __restrict__ A_log,
    float* __restrict__ cP, float* __restrict__ cS) {
  __shared__ float us[CLEN][16], ds[CLEN][16], bs[CLEN][16];
  __shared__ float xd12[CLEN][12], wdt[16][12], bds[16];
  int tid = threadIdx.x;
  int dl = tid >> 4, n = tid & 15;
  int d0 = blockIdx.x * 16;
  int t0 = blockIdx.y * CLEN;
  const us8 z8 = {0,0,0,0,0,0,0,0};
  const float4 z4 = {0.f,0.f,0.f,0.f};

  for (int i = tid; i < CLEN*2; i += 256) {
    int tt = i >> 1, h = (i & 1) * 8;
    int t = t0 + tt;
    us8 v = (t < L_TOK) ? *(const us8*)(ucb + (size_t)t*DI + d0 + h) : z8;
#pragma unroll
    for (int j = 0; j < 8; ++j) us[tt][h+j] = bf2f(v[j]);
  }
  for (int i = tid; i < CLEN*7; i += 256) {
    int tt = i / 7, q = i % 7;
    int t = t0 + tt;
    float4 v = (t < L_TOK) ? *(const float4*)(xdbl + (size_t)t*XDBL_N + q*4) : z4;
    if (q < 3) {
      xd12[tt][q*4+0]=v.x; xd12[tt][q*4+1]=v.y;
      xd12[tt][q*4+2]=v.z; xd12[tt][q*4+3]=v.w;
    } else {
      int c = (q-3)*4;
      bs[tt][c+0]=v.x; bs[tt][c+1]=v.y; bs[tt][c+2]=v.z; bs[tt][c+3]=v.w;
    }
  }
  if (tid < 192) wdt[tid/12][tid%12] = W_dt[(d0 + tid/12)*DTR + tid%12];
  if (tid < 16)  bds[tid] = b_dt[d0+tid];
  __syncthreads();
  for (int i = tid; i < CLEN*16; i += 256) {
    int tt = i >> 4, dd = i & 15;
    int t = t0 + tt;
    float v = 0.0f;
    if (t < L_TOK) {
      v = bds[dd];
#pragma unroll
      for (int r = 0; r < 12; ++r) v = fmaf(xd12[tt][r], wdt[dd][r], v);
      v = (v > 20.0f) ? v : log1pf(expf(v));
    }
    ds[tt][dd] = v;
  }
  __syncthreads();

  int d = d0 + dl;
  float a2 = -expf(A_log[d*DS + n]) * 1.44269504088896340736f;
  float s = 0.0f, P = 1.0f;
#pragma unroll 4
  for (int tt = 0; tt < CLEN; ++tt) {
    float dv = ds[tt][dl];
    float dA = exp2f(dv * a2);
    s = fmaf(dA, s, dv * bs[tt][n] * us[tt][dl]);
    P *= dA;
  }
  int o = (blockIdx.y * DI + d) * DS + n;
  cP[o] = P;
  cS[o] = s;
}

// ---------------------------------------------------------------------------
// scan_p3: carry-in combine over preceding chunks, recompute delta (identical
// code to p1 -> bit-identical values), re-scan, emit y (bf16).
// grid = (NDG, NCHUNK) = (24, 50), 256 thr.
// ---------------------------------------------------------------------------
__global__ __launch_bounds__(256) void scan_p3(
    const unsigned short* __restrict__ ucb,
    const float* __restrict__ xdbl, const unsigned short* __restrict__ xzb,
    const float* __restrict__ W_dt, const float* __restrict__ b_dt,
    const float* __restrict__ A_log, const float* __restrict__ Dp,
    const float* __restrict__ cP, const float* __restrict__ cS,
    unsigned short* __restrict__ yyb) {
  __shared__ float us[CLEN][16], ds[CLEN][16], bs[CLEN][16];
  __shared__ float cs[CLEN][16], zs[CLEN][16];
  __shared__ float xd12[CLEN][12], wdt[16][12], bds[16];
  int tid = threadIdx.x;
  int dl = tid >> 4, n = tid & 15;
  int d0 = blockIdx.x * 16;
  int cidx = blockIdx.y;
  int t0 = cidx * CLEN;
  int nt = min(CLEN, L_TOK - t0);
  int d = d0 + dl;
  const us8 z8 = {0,0,0,0,0,0,0,0};
  const float4 z4 = {0.f,0.f,0.f,0.f};

  float s = 0.0f;
  {
    int oo = d * DS + n;
#pragma unroll 8
    for (int c2 = 0; c2 < cidx; ++c2)
      s = fmaf(cP[(size_t)c2*(DI*DS) + oo], s, cS[(size_t)c2*(DI*DS) + oo]);
  }

  for (int i = tid; i < CLEN*2; i += 256) {
    int tt = i >> 1, h = (i & 1) * 8;
    int t = t0 + tt;
    bool ok = (t < L_TOK);
    us8 vu = ok ? *(const us8*)(ucb + (size_t)t*DI + d0 + h) : z8;
    us8 vz = ok ? *(const us8*)(xzb + (size_t)t*(2*DI) + DI + d0 + h) : z8;
#pragma unroll
    for (int j = 0; j < 8; ++j) {
      us[tt][h+j] = bf2f(vu[j]);
      zs[tt][h+j] = bf2f(vz[j]);
    }
  }
  for (int i = tid; i < CLEN*11; i += 256) {
    int tt = i / 11, q = i % 11;
    int t = t0 + tt;
    float4 v = (t < L_TOK) ? *(const float4*)(xdbl + (size_t)t*XDBL_N + q*4) : z4;
    if (q < 3) {
      xd12[tt][q*4+0]=v.x; xd12[tt][q*4+1]=v.y;
      xd12[tt][q*4+2]=v.z; xd12[tt][q*4+3]=v.w;
    } else if (q < 7) {
      int c = (q-3)*4;
      bs[tt][c+0]=v.x; bs[tt][c+1]=v.y; bs[tt][c+2]=v.z; bs[tt][c+3]=v.w;
    } else {
      int c = (q-7)*4;
      cs[tt][c+0]=v.x; cs[tt][c+1]=v.y; cs[tt][c+2]=v.z; cs[tt][c+3]=v.w;
    }
  }
  if (tid < 192) wdt[tid/12][tid%12] = W_dt[(d0 + tid/12)*DTR + tid%12];
  if (tid < 16)  bds[tid] = b_dt[d0+tid];
  __syncthreads();
  for (int i = tid; i < CLEN*16; i += 256) {
    int tt = i >> 4, dd = i & 15;
    int t = t0 + tt;
    float v = 0.0f;
    if (t < L_TOK) {
      v = bds[dd];
#pragma unroll
      for (int r = 0; r < 12; ++r) v = fmaf(xd12[tt][r], wdt[dd][r], v);
      v = (v > 20.0f) ? v : log1pf(expf(v));
    }
    ds[tt][dd] = v;
  }
  __syncthreads();

  float a2 = -expf(A_log[d*DS + n]) * 1.44269504088896340736f;
  float dpv = Dp[d];
#pragma unroll 4
  for (int tt = 0; tt < CLEN; ++tt) {
    float dv = ds[tt][dl], uu = us[tt][dl];
    float dA = exp2f(dv * a2);
    s = fmaf(dA, s, dv * bs[tt][n] * uu);
    float p = s * cs[tt][n];
    p += __shfl_xor(p, 1, 64);
    p += __shfl_xor(p, 2, 64);
    p += __shfl_xor(p, 4, 64);
    p += __shfl_xor(p, 8, 64);
    if (n == 0 && tt < nt) {
      float z = zs[tt][dl];
      float y = fmaf(uu, dpv, p);
      y *= z / (1.0f + expf(-z));
      yyb[(size_t)(t0 + tt)*DI + d] = f2bf(y);
    }
  }
}

// ---------------------------------------------------------------------------
// out projection: cur += yy(bf16) @ W_out(bf16)^T, split-K 6 (ksl=64),
// atomicAdd residual into cur.
// ---------------------------------------------------------------------------
__global__ __launch_bounds__(256) void mgemm_kernel(
    const unsigned short* __restrict__ A, int lda,
    const unsigned short* __restrict__ B, int ldb,
    float* __restrict__ C, int ldc,
    int M, int N, int ksl) {
  __shared__ unsigned short As[64*40];
  __shared__ unsigned short Bs[64*40];
  int tid = threadIdx.x;
  int m0 = blockIdx.y * 64, n0 = blockIdx.x * 64;
  int kbase = blockIdx.z * ksl;
  int wave = tid >> 6, lane = tid & 63;
  int wr = wave >> 1, wc = wave & 1;
  int srow = tid >> 2;
  int skq  = (tid & 3) * 8;
  f32x4 acc[2][2];
#pragma unroll
  for (int i = 0; i < 2; ++i)
#pragma unroll
    for (int j = 0; j < 2; ++j) acc[i][j] = (f32x4){0.f,0.f,0.f,0.f};

  int am = m0 + srow;
  int bn = n0 + srow;
  bool a_ok = (am < M), b_ok = (bn < N);
  const unsigned short* ap = A + (size_t)am*lda + kbase + skq;
  const unsigned short* bp = B + (size_t)bn*ldb + kbase + skq;
  const us8 z8 = {0,0,0,0,0,0,0,0};
  int l15 = lane & 15, lk = (lane >> 4) * 8;

  int nt = ksl >> 5;
  us8 av = a_ok ? *(const us8*)(ap) : z8;
  us8 bv = b_ok ? *(const us8*)(bp) : z8;

  for (int i = 0; i < nt; ++i) {
    *(us8*)&As[srow*40 + skq] = av;
    *(us8*)&Bs[srow*40 + skq] = bv;
    __syncthreads();
    bool pf = (i + 1 < nt);
    int k0n = (i + 1) << 5;
    av = (pf && a_ok) ? *(const us8*)(ap + k0n) : z8;
    bv = (pf && b_ok) ? *(const us8*)(bp + k0n) : z8;

    short8 af0 = *(const short8*)&As[(wr*32      + l15)*40 + lk];
    short8 af1 = *(const short8*)&As[(wr*32 + 16 + l15)*40 + lk];
    short8 bf0 = *(const short8*)&Bs[(wc*32      + l15)*40 + lk];
    short8 bf1 = *(const short8*)&Bs[(wc*32 + 16 + l15)*40 + lk];
    acc[0][0] = __builtin_amdgcn_mfma_f32_16x16x32_bf16(af0, bf0, acc[0][0], 0, 0, 0);
    acc[0][1] = __builtin_amdgcn_mfma_f32_16x16x32_bf16(af0, bf1, acc[0][1], 0, 0, 0);
    acc[1][0] = __builtin_amdgcn_mfma_f32_16x16x32_bf16(af1, bf0, acc[1][0], 0, 0, 0);
    acc[1][1] = __builtin_amdgcn_mfma_f32_16x16x32_bf16(af1, bf1, acc[1][1], 0, 0, 0);
    __syncthreads();
  }

#pragma unroll
  for (int r = 0; r < 2; ++r) {
#pragma unroll
    for (int c = 0; c < 2; ++c) {
      int col = n0 + wc*32 + c*16 + l15;
      if (col >= N) continue;
      int rowb = m0 + wr*32 + r*16 + (lane >> 4)*4;
#pragma unroll
      for (int j = 0; j < 4; ++j) {
        int row = rowb + j;
        if (row >= M) continue;
        atomicAdd(C + (size_t)row*ldc + col, acc[r][c][j]);
      }
    }
  }
}

// ---------------------------------------------------------------------------
extern "C" void kernel_launch(void* const* d_in, const int* in_sizes, int n_in,
                              void* d_out, int out_size, void* d_ws, size_t ws_size,
                              hipStream_t stream) {
  const float* x       = (const float*)d_in[0];
  const float* patch_w = (const float*)d_in[1];
  const float* patch_b = (const float*)d_in[2];
  const float* cls_tok = (const float*)d_in[3];
  const float* pos_emb = (const float*)d_in[4];
  const float* ln_g    = (const float*)d_in[5];
  const float* ln_b    = (const float*)d_in[6];
  const float* W_in    = (const float*)d_in[7];
  const float* Wc      = (const float*)d_in[8];
  const float* bc      = (const float*)d_in[9];
  const float* Wx      = (const float*)d_in[10];
  const float* W_dt    = (const float*)d_in[11];
  const float* b_dt    = (const float*)d_in[12];
  const float* A_log   = (const float*)d_in[13];
  const float* Dp      = (const float*)d_in[14];
  const float* W_out   = (const float*)d_in[15];
  const float* fn_g    = (const float*)d_in[16];
  const float* fn_b    = (const float*)d_in[17];

  float* ws = (float*)d_ws;
  float* cur   = ws;                                        // 1569*192 f32
  unsigned short* xzb = (unsigned short*)(cur + L_TOK*DM);  // 1569*768 bf16
  float* xdbl  = (float*)(xzb + L_TOK*2*DI);                // 1569*44  f32
  unsigned short* ucb  = (unsigned short*)(xdbl + L_TOK*XDBL_N); // bf16
  unsigned short* yyb  = ucb + L_TOK*DI;                    // bf16
  float* cP    = (float*)(yyb + L_TOK*DI);                  // 50*6144 f32
  float* cS    = cP + NCHUNK*DI*DS;
  unsigned short* pwb  = (unsigned short*)(cS + NCHUNK*DI*DS);
  unsigned short* winb = pwb  + PW_N;
  unsigned short* wxb  = winb + WIN_N;
  unsigned short* wob  = wxb  + WX_N;

  init_kernel<<<1024, 256, 0, stream>>>(
      cls_tok, patch_b, pos_emb, cur,
      patch_w, W_in, Wx, W_out, pwb, winb, wxb, wob);
  {
    dim3 grid(DM/64, (NPATCH + 63)/64, 8);
    patch_gemm<<<grid, 256, 0, stream>>>(x, pwb, cur + DM);
  }

  for (int dep = 0; dep < DEPTH; ++dep) {
    const float* g     = ln_g  + dep*DM;
    const float* bb    = ln_b  + dep*DM;
    const unsigned short* Win_l = winb + (size_t)dep*2*DI*DM;
    const float* Wc_l  = Wc    + (size_t)dep*DI*DCONV;
    const float* bc_l  = bc    + (size_t)dep*DI;
    const unsigned short* Wx_l  = wxb + (size_t)dep*XDBL_N*DI;
    const float* Wdt_l = W_dt  + (size_t)dep*DI*DTR;
    const float* bdt_l = b_dt  + (size_t)dep*DI;
    const float* Alog_l= A_log + (size_t)dep*DI*DS;
    const float* Dp_l  = Dp    + (size_t)dep*DI;
    const unsigned short* Wout_l= wob + (size_t)dep*DM*DI;

    // xz = LN(cur) @ W_in^T (BN=128; bf16 out; zeroes xdbl)
    {
      dim3 grid((2*DI)/128, (L_TOK + 63)/64);
      lnxz_kernel<<<grid, 256, 0, stream>>>(cur, g, bb, Win_l, xzb, xdbl);
    }
    // xdbl = silu(conv(u)) @ Wx^T, split-K 12; exports ucb (bf16)
    {
      dim3 grid(1, (L_TOK + 63)/64, 12);
      cgemm_kernel<<<grid, 256, 0, stream>>>(xzb, Wc_l, bc_l, Wx_l, xdbl, ucb);
    }
    // selective scan: local (p1) then carry+emit (p3, recomputes delta)
    {
      dim3 g1(NDG, NCHUNK);
      scan_p1<<<g1, 256, 0, stream>>>(ucb, xdbl, Wdt_l, bdt_l, Alog_l, cP, cS);
      scan_p3<<<g1, 256, 0, stream>>>(ucb, xdbl, xzb, Wdt_l, bdt_l, Alog_l,
                                      Dp_l, cP, cS, yyb);
    }
    // cur += yy @ W_out^T (split-K 6)
    {
      dim3 grid(DM/64, (L_TOK + 63)/64, 6);
      mgemm_kernel<<<grid, 256, 0, stream>>>(yyb, DI, Wout_l, DI, cur, DM,
                                             L_TOK, DM, DI/6);
    }
  }

  ln_kernel<<<L_TOK, 64, 0, stream>>>(cur, (float*)d_out, fn_g, fn_b);
}

// Round 17
// 473.344 us; speedup vs baseline: 1.0745x; 1.0745x over previous
//
#include <hip/hip_runtime.h>
#include <hip/hip_bf16.h>
#include <math.h>

#define L_TOK 1569
#define DM 192
#define DI 384
#define DS 16
#define DTR 12
#define DCONV 4
#define XDBL_N (DTR + 2*DS)   // 44
#define DEPTH 8
#define NCHUNK 50
#define CLEN 32
#define NPATCH 1568
#define NDG 24                // scan d-groups (384/16)

typedef __attribute__((ext_vector_type(8))) short short8;
typedef __attribute__((ext_vector_type(8))) unsigned short us8;
typedef __attribute__((ext_vector_type(4))) float f32x4;

__device__ __forceinline__ unsigned short f2bf(float f) {
  unsigned int u = __float_as_uint(f);
  u += 0x7FFFu + ((u >> 16) & 1u);   // round-to-nearest-even
  return (unsigned short)(u >> 16);
}

__device__ __forceinline__ float bf2f(unsigned short h) {
  return __uint_as_float(((unsigned int)h) << 16);
}

// sizes (elements) of converted weight blocks
#define PW_N  (192*768)
#define WIN_N (DEPTH*2*DI*DM)
#define WX_N  (DEPTH*XDBL_N*DI)
#define WO_N  (DEPTH*DM*DI)

__device__ __forceinline__ void cv8(const float* __restrict__ s,
                                    unsigned short* __restrict__ d, int i) {
  float4 a = *(const float4*)(s + (size_t)i*8);
  float4 b = *(const float4*)(s + (size_t)i*8 + 4);
  us8 o;
  o[0]=f2bf(a.x); o[1]=f2bf(a.y); o[2]=f2bf(a.z); o[3]=f2bf(a.w);
  o[4]=f2bf(b.x); o[5]=f2bf(b.y); o[6]=f2bf(b.z); o[7]=f2bf(b.w);
  *(us8*)(d + (size_t)i*8) = o;
}

// ---------------------------------------------------------------------------
// init: cur[tok][e] = pos + (tok==0 ? cls : patch_b); also converts all MFMA
// B-operand weights to bf16 (one-time, stream-ordered before first use).
// ---------------------------------------------------------------------------
__global__ __launch_bounds__(256) void init_kernel(
    const float* __restrict__ cls, const float* __restrict__ pb,
    const float* __restrict__ pos, float* __restrict__ curp,
    const float* __restrict__ pw,  const float* __restrict__ wi,
    const float* __restrict__ wx,  const float* __restrict__ wo,
    unsigned short* __restrict__ pwb, unsigned short* __restrict__ winb,
    unsigned short* __restrict__ wxb, unsigned short* __restrict__ wob) {
  int tid0 = blockIdx.x * 256 + threadIdx.x;
  int NT = gridDim.x * 256;
  const int initN = (L_TOK * DM) / 4;
  for (int gid = tid0; gid < initN; gid += NT) {
    int e4 = gid * 4;
    int tok = e4 / DM;
    int col = e4 % DM;
    float4 pv = *(const float4*)(pos + e4);
    float4 av = (tok == 0) ? *(const float4*)(cls + col)
                           : *(const float4*)(pb + col);
    float4 o = {pv.x + av.x, pv.y + av.y, pv.z + av.z, pv.w + av.w};
    *(float4*)(curp + e4) = o;
  }
  for (int i = tid0; i < PW_N/8;  i += NT) cv8(pw, pwb, i);
  for (int i = tid0; i < WIN_N/8; i += NT) cv8(wi, winb, i);
  for (int i = tid0; i < WX_N/8;  i += NT) cv8(wx, wxb, i);
  for (int i = tid0; i < WO_N/8;  i += NT) cv8(wo, wob, i);
}

// ---------------------------------------------------------------------------
// Final LayerNorm. One wave per token.
// ---------------------------------------------------------------------------
__global__ __launch_bounds__(64) void ln_kernel(
    const float* __restrict__ in, float* __restrict__ out,
    const float* __restrict__ g, const float* __restrict__ b) {
  int tokn = blockIdx.x;
  int lane = threadIdx.x;
  const float* row = in + (size_t)tokn*DM;
  float x0 = row[lane], x1 = row[lane+64], x2 = row[lane+128];
  float s = x0 + x1 + x2;
  float s2 = x0*x0 + x1*x1 + x2*x2;
#pragma unroll
  for (int off = 1; off < 64; off <<= 1) {
    s  += __shfl_xor(s,  off, 64);
    s2 += __shfl_xor(s2, off, 64);
  }
  float m = s * (1.0f/192.0f);
  float v = s2 * (1.0f/192.0f) - m*m;
  float rs = rsqrtf(v + 1e-5f);
  float* orow = out + (size_t)tokn*DM;
  orow[lane]     = (x0 - m)*rs*g[lane]     + b[lane];
  orow[lane+64]  = (x1 - m)*rs*g[lane+64]  + b[lane+64];
  orow[lane+128] = (x2 - m)*rs*g[lane+128] + b[lane+128];
}

// ---------------------------------------------------------------------------
// Patch GEMM, im2col fused into A-staging, bf16 weights:
// cur[1..][:] += X_patch @ patch_w^T. M=1568, N=192, K=768, split-K 4.
// ---------------------------------------------------------------------------
__device__ __forceinline__ float4 ldx4(const float* __restrict__ x,
                                       int pt, int hh, int w, int k) {
  int c = k >> 8, p = (k >> 4) & 15, q = k & 15;
  return *(const float4*)(x + ((size_t)(c*8 + pt)*224 + hh*16 + p)*224
                            + w*16 + q);
}

__global__ __launch_bounds__(256) void patch_gemm(
    const float* __restrict__ x, const unsigned short* __restrict__ pw,
    float* __restrict__ C) {
  __shared__ unsigned short As[64*40];
  __shared__ unsigned short Bs[64*40];
  int tid = threadIdx.x;
  int m0 = blockIdx.y * 64, n0 = blockIdx.x * 64;
  int kbase = blockIdx.z * 192;
  int wave = tid >> 6, lane = tid & 63;
  int wr = wave >> 1, wc = wave & 1;
  int srow = tid >> 2;
  int skq  = (tid & 3) * 8;
  f32x4 acc[2][2];
#pragma unroll
  for (int i = 0; i < 2; ++i)
#pragma unroll
    for (int j = 0; j < 2; ++j) acc[i][j] = (f32x4){0.f,0.f,0.f,0.f};

  int am = m0 + srow;
  bool a_ok = (am < NPATCH);
  int am_s = a_ok ? am : 0;
  int pt = am_s / 196, hw = am_s % 196, hh = hw / 14, w = hw % 14;
  int bn = n0 + srow;
  const unsigned short* bp = pw + (size_t)bn*768 + kbase + skq;
  const float4 z4 = {0.f,0.f,0.f,0.f};
  const us8 z8 = {0,0,0,0,0,0,0,0};
  int l15 = lane & 15, lk = (lane >> 4) * 8;

  const int nt = 6;   // 192/32
  float4 a0 = a_ok ? ldx4(x, pt, hh, w, kbase + skq)     : z4;
  float4 a1 = a_ok ? ldx4(x, pt, hh, w, kbase + skq + 4) : z4;
  us8 bv = *(const us8*)(bp);

  for (int i = 0; i < nt; ++i) {
    {
      short8 pa;
      pa[0]=f2bf(a0.x); pa[1]=f2bf(a0.y); pa[2]=f2bf(a0.z); pa[3]=f2bf(a0.w);
      pa[4]=f2bf(a1.x); pa[5]=f2bf(a1.y); pa[6]=f2bf(a1.z); pa[7]=f2bf(a1.w);
      *(short8*)&As[srow*40 + skq] = pa;
      *(us8*)&Bs[srow*40 + skq] = bv;
    }
    __syncthreads();
    bool pf = (i + 1 < nt);
    int kn = kbase + ((i + 1) << 5) + skq;
    a0 = (pf && a_ok) ? ldx4(x, pt, hh, w, kn)     : z4;
    a1 = (pf && a_ok) ? ldx4(x, pt, hh, w, kn + 4) : z4;
    bv = pf ? *(const us8*)(bp + ((i+1)<<5)) : z8;

    short8 af0 = *(const short8*)&As[(wr*32      + l15)*40 + lk];
    short8 af1 = *(const short8*)&As[(wr*32 + 16 + l15)*40 + lk];
    short8 bf0 = *(const short8*)&Bs[(wc*32      + l15)*40 + lk];
    short8 bf1 = *(const short8*)&Bs[(wc*32 + 16 + l15)*40 + lk];
    acc[0][0] = __builtin_amdgcn_mfma_f32_16x16x32_bf16(af0, bf0, acc[0][0], 0, 0, 0);
    acc[0][1] = __builtin_amdgcn_mfma_f32_16x16x32_bf16(af0, bf1, acc[0][1], 0, 0, 0);
    acc[1][0] = __builtin_amdgcn_mfma_f32_16x16x32_bf16(af1, bf0, acc[1][0], 0, 0, 0);
    acc[1][1] = __builtin_amdgcn_mfma_f32_16x16x32_bf16(af1, bf1, acc[1][1], 0, 0, 0);
    __syncthreads();
  }

#pragma unroll
  for (int r = 0; r < 2; ++r) {
#pragma unroll
    for (int c = 0; c < 2; ++c) {
      int col = n0 + wc*32 + c*16 + l15;
      int rowb = m0 + wr*32 + r*16 + (lane >> 4)*4;
#pragma unroll
      for (int j = 0; j < 4; ++j) {
        int row = rowb + j;
        if (row < NPATCH)
          atomicAdd(C + (size_t)row*DM + col, acc[r][c][j]);
      }
    }
  }
}

// ---------------------------------------------------------------------------
// Fused LN + xz GEMM, BN=128 (LN computed once per 128 output cols).
// grid (6, 25). Output xz bf16. Zeroes xdbl (bx==0).
// ---------------------------------------------------------------------------
__global__ __launch_bounds__(256) void lnxz_kernel(
    const float* __restrict__ cur, const float* __restrict__ g,
    const float* __restrict__ b, const unsigned short* __restrict__ W,
    unsigned short* __restrict__ xzb, float* __restrict__ xdbl_z) {
  __shared__ unsigned short As[64][200];
  __shared__ unsigned short Bs[128][200];
  __shared__ float gs[192], bs2[192];
  int tid = threadIdx.x;
  int m0 = blockIdx.y * 64, n0 = blockIdx.x * 128;
  int wave = tid >> 6, lane = tid & 63;
  int wr = wave >> 1, wcq = wave & 1;
  int l15 = lane & 15, lk = (lane >> 4) * 8;

  for (int i = tid; i < 192; i += 256) { gs[i] = g[i]; bs2[i] = b[i]; }

  if (blockIdx.x == 0) {
    for (int i = tid; i < 64*11; i += 256) {
      int r = i / 11, q = i % 11;
      int row = m0 + r;
      if (row < L_TOK) {
        float4 z = {0.f,0.f,0.f,0.f};
        *(float4*)(xdbl_z + (size_t)row*XDBL_N + q*4) = z;
      }
    }
  }

  int r = tid >> 2, c0 = (tid & 3) * 48;
  float v[48];
  {
    int row = m0 + r;
    if (row < L_TOK) {
      const float* rp = cur + (size_t)row*DM + c0;
#pragma unroll
      for (int j = 0; j < 12; ++j) {
        float4 t4 = *(const float4*)(rp + j*4);
        v[j*4+0]=t4.x; v[j*4+1]=t4.y; v[j*4+2]=t4.z; v[j*4+3]=t4.w;
      }
    } else {
#pragma unroll
      for (int j = 0; j < 48; ++j) v[j] = 0.f;
    }
  }
  float s = 0.f, s2 = 0.f;
#pragma unroll
  for (int j = 0; j < 48; ++j) { s += v[j]; s2 += v[j]*v[j]; }
  s  += __shfl_xor(s, 1, 64); s2 += __shfl_xor(s2, 1, 64);
  s  += __shfl_xor(s, 2, 64); s2 += __shfl_xor(s2, 2, 64);
  float mu = s * (1.0f/192.0f);
  float var = s2 * (1.0f/192.0f) - mu*mu;
  float rsd = rsqrtf(var + 1e-5f);

  __syncthreads();
#pragma unroll
  for (int j = 0; j < 48; ++j) {
    int k = c0 + j;
    As[r][k] = f2bf((v[j] - mu)*rsd*gs[k] + bs2[k]);
  }
  for (int i = tid; i < 128*24; i += 256) {
    int row = i / 24, q = i % 24;
    *(us8*)&Bs[row][q*8] = *(const us8*)(W + (size_t)(n0 + row)*DM + q*8);
  }
  __syncthreads();

  f32x4 acc[2][4];
#pragma unroll
  for (int i = 0; i < 2; ++i)
#pragma unroll
    for (int j = 0; j < 4; ++j) acc[i][j] = (f32x4){0.f,0.f,0.f,0.f};

#pragma unroll
  for (int kk = 0; kk < 6; ++kk) {
    short8 af0 = *(const short8*)&As[wr*32      + l15][kk*32 + lk];
    short8 af1 = *(const short8*)&As[wr*32 + 16 + l15][kk*32 + lk];
#pragma unroll
    for (int cc = 0; cc < 4; ++cc) {
      short8 bf = *(const short8*)&Bs[wcq*64 + cc*16 + l15][kk*32 + lk];
      acc[0][cc] = __builtin_amdgcn_mfma_f32_16x16x32_bf16(af0, bf, acc[0][cc], 0, 0, 0);
      acc[1][cc] = __builtin_amdgcn_mfma_f32_16x16x32_bf16(af1, bf, acc[1][cc], 0, 0, 0);
    }
  }

#pragma unroll
  for (int rr = 0; rr < 2; ++rr) {
#pragma unroll
    for (int cc = 0; cc < 4; ++cc) {
      int col = n0 + wcq*64 + cc*16 + l15;
      int rowb = m0 + wr*32 + rr*16 + (lane >> 4)*4;
#pragma unroll
      for (int j = 0; j < 4; ++j) {
        int row = rowb + j;
        if (row < L_TOK)
          xzb[(size_t)row*(2*DI) + col] = f2bf(acc[rr][cc][j]);
      }
    }
  }
}

// ---------------------------------------------------------------------------
// xdbl GEMM, conv+SiLU fused in A-staging; bf16 Wx; split-K 12 (one k-step).
// Exports u (bf16) to ucb. xdbl (f32) zero-init by lnxz. grid = (1, 25, 12).
// ---------------------------------------------------------------------------
__global__ __launch_bounds__(256) void cgemm_kernel(
    const unsigned short* __restrict__ xzb,
    const float* __restrict__ Wc, const float* __restrict__ bc,
    const unsigned short* __restrict__ B, float* __restrict__ C,
    unsigned short* __restrict__ ucb) {
  __shared__ unsigned short As[64*40];
  __shared__ unsigned short Bs[64*40];
  __shared__ float wcs[32][4];
  __shared__ float bcs[32];
  const int M = L_TOK, N = XDBL_N;
  int tid = threadIdx.x;
  int m0 = blockIdx.y * 64;
  int kbase = blockIdx.z * 32;
  int wave = tid >> 6, lane = tid & 63;
  int wr = wave >> 1, wcq = wave & 1;
  int srow = tid >> 2;
  int skq  = (tid & 3) * 8;
  if (tid < 32) {
    *(float4*)wcs[tid] = *(const float4*)(Wc + (size_t)(kbase + tid)*4);
    bcs[tid] = bc[kbase + tid];
  }

  int t = m0 + srow;
  bool a_ok = (t < M);
  bool b_ok = (srow < N);
  const unsigned short* bp = B + (size_t)srow*DI + kbase + skq;
  const us8 z8 = {0,0,0,0,0,0,0,0};
  int l15 = lane & 15, lk = (lane >> 4) * 8;
  int cg = kbase + skq;

  us8 tap[4];
#pragma unroll
  for (int j = 0; j < 4; ++j) {
    int ts = t - 3 + j;
    tap[j] = (a_ok && ts >= 0)
               ? *(const us8*)(xzb + (size_t)ts*(2*DI) + cg) : z8;
  }
  us8 bv = b_ok ? *(const us8*)(bp) : z8;
  __syncthreads();   // wcs/bcs ready

  short8 pa;
#pragma unroll
  for (int c = 0; c < 8; ++c) {
    float u = bcs[skq + c];
#pragma unroll
    for (int j = 0; j < 4; ++j)
      u = fmaf(bf2f(tap[j][c]), wcs[skq + c][j], u);
    u = u / (1.0f + expf(-u));
    pa[c] = (short)f2bf(u);
  }
  if (a_ok)
    *(short8*)(ucb + (size_t)t*DI + cg) = pa;
  *(short8*)&As[srow*40 + skq] = pa;
  *(us8*)&Bs[srow*40 + skq] = bv;
  __syncthreads();

  f32x4 acc[2][2];
#pragma unroll
  for (int i = 0; i < 2; ++i)
#pragma unroll
    for (int j = 0; j < 2; ++j) acc[i][j] = (f32x4){0.f,0.f,0.f,0.f};
  short8 af0 = *(const short8*)&As[(wr*32      + l15)*40 + lk];
  short8 af1 = *(const short8*)&As[(wr*32 + 16 + l15)*40 + lk];
  short8 bf0 = *(const short8*)&Bs[(wcq*32      + l15)*40 + lk];
  short8 bf1 = *(const short8*)&Bs[(wcq*32 + 16 + l15)*40 + lk];
  acc[0][0] = __builtin_amdgcn_mfma_f32_16x16x32_bf16(af0, bf0, acc[0][0], 0, 0, 0);
  acc[0][1] = __builtin_amdgcn_mfma_f32_16x16x32_bf16(af0, bf1, acc[0][1], 0, 0, 0);
  acc[1][0] = __builtin_amdgcn_mfma_f32_16x16x32_bf16(af1, bf0, acc[1][0], 0, 0, 0);
  acc[1][1] = __builtin_amdgcn_mfma_f32_16x16x32_bf16(af1, bf1, acc[1][1], 0, 0, 0);

#pragma unroll
  for (int r = 0; r < 2; ++r) {
#pragma unroll
    for (int c = 0; c < 2; ++c) {
      int col = wcq*32 + c*16 + l15;
      if (col >= N) continue;
      int rowb = m0 + wr*32 + r*16 + (lane >> 4)*4;
#pragma unroll
      for (int j = 0; j < 4; ++j) {
        int row = rowb + j;
        if (row >= M) continue;
        atomicAdd(C + (size_t)row*XDBL_N + col, acc[r][c][j]);
      }
    }
  }
}

// ---------------------------------------------------------------------------
// scan_p1: per-chunk local scan from zero state (CLEN=32). Exports delta bf16.
// grid = (NDG, NCHUNK) = (24, 50), 256 thr = 16d x 16n.
// ---------------------------------------------------------------------------
__global__ __launch_bounds__(256) void scan_p1(
    const unsigned short* __restrict__ ucb, const float* __restrict__ xdbl,
    const float* __restrict__ W_dt, const float* __restrict__ b_dt,
    const float* __restrict__ A_log,
    float* __restrict__ cP, float* __restrict__ cS,
    unsigned short* __restrict__ dltb) {
  __shared__ float us[CLEN][16], ds[CLEN][16], bs[CLEN][16];
  __shared__ float xd12[CLEN][12], wdt[16][12], bds[16];
  int tid = threadIdx.x;
  int dl = tid >> 4, n = tid & 15;
  int d0 = blockIdx.x * 16;
  int t0 = blockIdx.y * CLEN;
  const us8 z8 = {0,0,0,0,0,0,0,0};
  const float4 z4 = {0.f,0.f,0.f,0.f};

  for (int i = tid; i < CLEN*2; i += 256) {
    int tt = i >> 1, h = (i & 1) * 8;
    int t = t0 + tt;
    us8 v = (t < L_TOK) ? *(const us8*)(ucb + (size_t)t*DI + d0 + h) : z8;
#pragma unroll
    for (int j = 0; j < 8; ++j) us[tt][h+j] = bf2f(v[j]);
  }
  for (int i = tid; i < CLEN*7; i += 256) {
    int tt = i / 7, q = i % 7;
    int t = t0 + tt;
    float4 v = (t < L_TOK) ? *(const float4*)(xdbl + (size_t)t*XDBL_N + q*4) : z4;
    if (q < 3) {
      xd12[tt][q*4+0]=v.x; xd12[tt][q*4+1]=v.y;
      xd12[tt][q*4+2]=v.z; xd12[tt][q*4+3]=v.w;
    } else {
      int c = (q-3)*4;
      bs[tt][c+0]=v.x; bs[tt][c+1]=v.y; bs[tt][c+2]=v.z; bs[tt][c+3]=v.w;
    }
  }
  if (tid < 192) wdt[tid/12][tid%12] = W_dt[(d0 + tid/12)*DTR + tid%12];
  if (tid < 16)  bds[tid] = b_dt[d0+tid];
  __syncthreads();
  for (int i = tid; i < CLEN*16; i += 256) {
    int tt = i >> 4, dd = i & 15;
    int t = t0 + tt;
    float v = 0.0f;
    if (t < L_TOK) {
      v = bds[dd];
#pragma unroll
      for (int r = 0; r < 12; ++r) v = fmaf(xd12[tt][r], wdt[dd][r], v);
      v = (v > 20.0f) ? v : log1pf(expf(v));
      unsigned short hb = f2bf(v);
      dltb[(size_t)t*DI + d0 + dd] = hb;
      v = bf2f(hb);   // use rounded value so p1/p3 scans agree exactly
    }
    ds[tt][dd] = v;
  }
  __syncthreads();

  int d = d0 + dl;
  float a2 = -expf(A_log[d*DS + n]) * 1.44269504088896340736f;
  float s = 0.0f, P = 1.0f;
#pragma unroll 4
  for (int tt = 0; tt < CLEN; ++tt) {
    float dv = ds[tt][dl];
    float dA = exp2f(dv * a2);
    s = fmaf(dA, s, dv * bs[tt][n] * us[tt][dl]);
    P *= dA;
  }
  int o = (blockIdx.y * DI + d) * DS + n;
  cP[o] = P;
  cS[o] = s;
}

// ---------------------------------------------------------------------------
// scan_p3: carry-in combine over preceding chunks, re-scan, emit y (bf16).
// grid = (NDG, NCHUNK) = (24, 50), 256 thr.
// ---------------------------------------------------------------------------
__global__ __launch_bounds__(256) void scan_p3(
    const unsigned short* __restrict__ ucb,
    const unsigned short* __restrict__ dltb,
    const float* __restrict__ xdbl, const unsigned short* __restrict__ xzb,
    const float* __restrict__ A_log, const float* __restrict__ Dp,
    const float* __restrict__ cP, const float* __restrict__ cS,
    unsigned short* __restrict__ yyb) {
  __shared__ float us[CLEN][16], ds[CLEN][16], bs[CLEN][16];
  __shared__ float cs[CLEN][16], zs[CLEN][16];
  int tid = threadIdx.x;
  int dl = tid >> 4, n = tid & 15;
  int d0 = blockIdx.x * 16;
  int cidx = blockIdx.y;
  int t0 = cidx * CLEN;
  int nt = min(CLEN, L_TOK - t0);
  int d = d0 + dl;
  const us8 z8 = {0,0,0,0,0,0,0,0};
  const float4 z4 = {0.f,0.f,0.f,0.f};

  float s = 0.0f;
  {
    int oo = d * DS + n;
#pragma unroll 8
    for (int c2 = 0; c2 < cidx; ++c2)
      s = fmaf(cP[(size_t)c2*(DI*DS) + oo], s, cS[(size_t)c2*(DI*DS) + oo]);
  }

  for (int i = tid; i < CLEN*2; i += 256) {
    int tt = i >> 1, h = (i & 1) * 8;
    int t = t0 + tt;
    bool ok = (t < L_TOK);
    us8 vu = ok ? *(const us8*)(ucb  + (size_t)t*DI + d0 + h) : z8;
    us8 vd = ok ? *(const us8*)(dltb + (size_t)t*DI + d0 + h) : z8;
    us8 vz = ok ? *(const us8*)(xzb  + (size_t)t*(2*DI) + DI + d0 + h) : z8;
#pragma unroll
    for (int j = 0; j < 8; ++j) {
      us[tt][h+j] = bf2f(vu[j]);
      ds[tt][h+j] = bf2f(vd[j]);
      zs[tt][h+j] = bf2f(vz[j]);
    }
  }
  for (int i = tid; i < CLEN*8; i += 256) {
    int tt = i >> 3, q = i & 7;
    int t = t0 + tt;
    float4 v = (t < L_TOK)
                 ? *(const float4*)(xdbl + (size_t)t*XDBL_N + 12 + q*4) : z4;
    if (q < 4) {
      int c = q*4;
      bs[tt][c+0]=v.x; bs[tt][c+1]=v.y; bs[tt][c+2]=v.z; bs[tt][c+3]=v.w;
    } else {
      int c = (q-4)*4;
      cs[tt][c+0]=v.x; cs[tt][c+1]=v.y; cs[tt][c+2]=v.z; cs[tt][c+3]=v.w;
    }
  }
  __syncthreads();

  float a2 = -expf(A_log[d*DS + n]) * 1.44269504088896340736f;
  float dpv = Dp[d];
#pragma unroll 4
  for (int tt = 0; tt < CLEN; ++tt) {
    float dv = ds[tt][dl], uu = us[tt][dl];
    float dA = exp2f(dv * a2);
    s = fmaf(dA, s, dv * bs[tt][n] * uu);
    float p = s * cs[tt][n];
    p += __shfl_xor(p, 1, 64);
    p += __shfl_xor(p, 2, 64);
    p += __shfl_xor(p, 4, 64);
    p += __shfl_xor(p, 8, 64);
    if (n == 0 && tt < nt) {
      float z = zs[tt][dl];
      float y = fmaf(uu, dpv, p);
      y *= z / (1.0f + expf(-z));
      yyb[(size_t)(t0 + tt)*DI + d] = f2bf(y);
    }
  }
}

// ---------------------------------------------------------------------------
// out projection: cur += yy(bf16) @ W_out(bf16)^T, split-K 4, atomicAdd.
// ---------------------------------------------------------------------------
__global__ __launch_bounds__(256) void mgemm_kernel(
    const unsigned short* __restrict__ A, int lda,
    const unsigned short* __restrict__ B, int ldb,
    float* __restrict__ C, int ldc,
    int M, int N, int ksl) {
  __shared__ unsigned short As[64*40];
  __shared__ unsigned short Bs[64*40];
  int tid = threadIdx.x;
  int m0 = blockIdx.y * 64, n0 = blockIdx.x * 64;
  int kbase = blockIdx.z * ksl;
  int wave = tid >> 6, lane = tid & 63;
  int wr = wave >> 1, wc = wave & 1;
  int srow = tid >> 2;
  int skq  = (tid & 3) * 8;
  f32x4 acc[2][2];
#pragma unroll
  for (int i = 0; i < 2; ++i)
#pragma unroll
    for (int j = 0; j < 2; ++j) acc[i][j] = (f32x4){0.f,0.f,0.f,0.f};

  int am = m0 + srow;
  int bn = n0 + srow;
  bool a_ok = (am < M), b_ok = (bn < N);
  const unsigned short* ap = A + (size_t)am*lda + kbase + skq;
  const unsigned short* bp = B + (size_t)bn*ldb + kbase + skq;
  const us8 z8 = {0,0,0,0,0,0,0,0};
  int l15 = lane & 15, lk = (lane >> 4) * 8;

  int nt = ksl >> 5;
  us8 av = a_ok ? *(const us8*)(ap) : z8;
  us8 bv = b_ok ? *(const us8*)(bp) : z8;

  for (int i = 0; i < nt; ++i) {
    *(us8*)&As[srow*40 + skq] = av;
    *(us8*)&Bs[srow*40 + skq] = bv;
    __syncthreads();
    bool pf = (i + 1 < nt);
    int k0n = (i + 1) << 5;
    av = (pf && a_ok) ? *(const us8*)(ap + k0n) : z8;
    bv = (pf && b_ok) ? *(const us8*)(bp + k0n) : z8;

    short8 af0 = *(const short8*)&As[(wr*32      + l15)*40 + lk];
    short8 af1 = *(const short8*)&As[(wr*32 + 16 + l15)*40 + lk];
    short8 bf0 = *(const short8*)&Bs[(wc*32      + l15)*40 + lk];
    short8 bf1 = *(const short8*)&Bs[(wc*32 + 16 + l15)*40 + lk];
    acc[0][0] = __builtin_amdgcn_mfma_f32_16x16x32_bf16(af0, bf0, acc[0][0], 0, 0, 0);
    acc[0][1] = __builtin_amdgcn_mfma_f32_16x16x32_bf16(af0, bf1, acc[0][1], 0, 0, 0);
    acc[1][0] = __builtin_amdgcn_mfma_f32_16x16x32_bf16(af1, bf0, acc[1][0], 0, 0, 0);
    acc[1][1] = __builtin_amdgcn_mfma_f32_16x16x32_bf16(af1, bf1, acc[1][1], 0, 0, 0);
    __syncthreads();
  }

#pragma unroll
  for (int r = 0; r < 2; ++r) {
#pragma unroll
    for (int c = 0; c < 2; ++c) {
      int col = n0 + wc*32 + c*16 + l15;
      if (col >= N) continue;
      int rowb = m0 + wr*32 + r*16 + (lane >> 4)*4;
#pragma unroll
      for (int j = 0; j < 4; ++j) {
        int row = rowb + j;
        if (row >= M) continue;
        atomicAdd(C + (size_t)row*ldc + col, acc[r][c][j]);
      }
    }
  }
}

// ---------------------------------------------------------------------------
extern "C" void kernel_launch(void* const* d_in, const int* in_sizes, int n_in,
                              void* d_out, int out_size, void* d_ws, size_t ws_size,
                              hipStream_t stream) {
  const float* x       = (const float*)d_in[0];
  const float* patch_w = (const float*)d_in[1];
  const float* patch_b = (const float*)d_in[2];
  const float* cls_tok = (const float*)d_in[3];
  const float* pos_emb = (const float*)d_in[4];
  const float* ln_g    = (const float*)d_in[5];
  const float* ln_b    = (const float*)d_in[6];
  const float* W_in    = (const float*)d_in[7];
  const float* Wc      = (const float*)d_in[8];
  const float* bc      = (const float*)d_in[9];
  const float* Wx      = (const float*)d_in[10];
  const float* W_dt    = (const float*)d_in[11];
  const float* b_dt    = (const float*)d_in[12];
  const float* A_log   = (const float*)d_in[13];
  const float* Dp      = (const float*)d_in[14];
  const float* W_out   = (const float*)d_in[15];
  const float* fn_g    = (const float*)d_in[16];
  const float* fn_b    = (const float*)d_in[17];

  float* ws = (float*)d_ws;
  float* cur   = ws;                                        // 1569*192 f32
  unsigned short* xzb = (unsigned short*)(cur + L_TOK*DM);  // 1569*768 bf16
  float* xdbl  = (float*)(xzb + L_TOK*2*DI);                // 1569*44  f32
  unsigned short* ucb  = (unsigned short*)(xdbl + L_TOK*XDBL_N); // bf16
  unsigned short* dltb = ucb  + L_TOK*DI;                   // bf16
  unsigned short* yyb  = dltb + L_TOK*DI;                   // bf16
  float* cP    = (float*)(yyb + L_TOK*DI);                  // 50*6144 f32
  float* cS    = cP + NCHUNK*DI*DS;
  unsigned short* pwb  = (unsigned short*)(cS + NCHUNK*DI*DS);
  unsigned short* winb = pwb  + PW_N;
  unsigned short* wxb  = winb + WIN_N;
  unsigned short* wob  = wxb  + WX_N;

  init_kernel<<<1024, 256, 0, stream>>>(
      cls_tok, patch_b, pos_emb, cur,
      patch_w, W_in, Wx, W_out, pwb, winb, wxb, wob);
  {
    dim3 grid(DM/64, (NPATCH + 63)/64, 4);
    patch_gemm<<<grid, 256, 0, stream>>>(x, pwb, cur + DM);
  }

  for (int dep = 0; dep < DEPTH; ++dep) {
    const float* g     = ln_g  + dep*DM;
    const float* bb    = ln_b  + dep*DM;
    const unsigned short* Win_l = winb + (size_t)dep*2*DI*DM;
    const float* Wc_l  = Wc    + (size_t)dep*DI*DCONV;
    const float* bc_l  = bc    + (size_t)dep*DI;
    const unsigned short* Wx_l  = wxb + (size_t)dep*XDBL_N*DI;
    const float* Wdt_l = W_dt  + (size_t)dep*DI*DTR;
    const float* bdt_l = b_dt  + (size_t)dep*DI;
    const float* Alog_l= A_log + (size_t)dep*DI*DS;
    const float* Dp_l  = Dp    + (size_t)dep*DI;
    const unsigned short* Wout_l= wob + (size_t)dep*DM*DI;

    // xz = LN(cur) @ W_in^T (BN=128; bf16 out; zeroes xdbl)
    {
      dim3 grid((2*DI)/128, (L_TOK + 63)/64);
      lnxz_kernel<<<grid, 256, 0, stream>>>(cur, g, bb, Win_l, xzb, xdbl);
    }
    // xdbl = silu(conv(u)) @ Wx^T, split-K 12; exports ucb (bf16)
    {
      dim3 grid(1, (L_TOK + 63)/64, 12);
      cgemm_kernel<<<grid, 256, 0, stream>>>(xzb, Wc_l, bc_l, Wx_l, xdbl, ucb);
    }
    // selective scan: local (p1, exports delta bf16) then carry+emit (p3)
    {
      dim3 g1(NDG, NCHUNK);
      scan_p1<<<g1, 256, 0, stream>>>(ucb, xdbl, Wdt_l, bdt_l, Alog_l, cP, cS, dltb);
      scan_p3<<<g1, 256, 0, stream>>>(ucb, dltb, xdbl, xzb, Alog_l, Dp_l, cP, cS, yyb);
    }
    // cur += yy @ W_out^T (split-K 4)
    {
      dim3 grid(DM/64, (L_TOK + 63)/64, 4);
      mgemm_kernel<<<grid, 256, 0, stream>>>(yyb, DI, Wout_l, DI, cur, DM,
                                             L_TOK, DM, DI/4);
    }
  }

  ln_kernel<<<L_TOK, 64, 0, stream>>>(cur, (float*)d_out, fn_g, fn_b);
}